// Round 1
// baseline (147.847 us; speedup 1.0000x reference)
//
#include <hip/hip_runtime.h>
#include <hip/hip_bf16.h>

// BEV pool v2: segment-sum of depth[rd[p]] * feat_row[rf[p]] into BEV grid.
// One thread per (interval, channel). C=80, n_bev = out_size / 80.

#define C_CH 80

__global__ void bev_pool_interval_kernel(
    const float* __restrict__ depth,      // flat [B*N_CAM*D*HF*WF]
    const float* __restrict__ feat,       // flat rows [n_rows][80]
    const int*   __restrict__ ranks_depth,
    const int*   __restrict__ ranks_feat,
    const int*   __restrict__ ranks_bev,
    const int*   __restrict__ interval_starts,
    const int*   __restrict__ interval_lengths,
    int n_intervals,
    int n_bev,                            // 16384
    float* __restrict__ out)              // [80][n_bev] (C-major per output transpose)
{
    int idx = blockIdx.x * blockDim.x + threadIdx.x;
    int total = n_intervals * C_CH;
    if (idx >= total) return;

    int interval = idx / C_CH;
    int c        = idx - interval * C_CH;

    int start = interval_starts[interval];
    int len   = interval_lengths[interval];

    float acc = 0.0f;
    int p = start;
    // Unroll-by-4 for a bit of ILP in the gather stream.
    int len4 = len & ~3;
    for (int i = 0; i < len4; i += 4) {
        int p0 = p + i, p1 = p + i + 1, p2 = p + i + 2, p3 = p + i + 3;
        float d0 = depth[ranks_depth[p0]];
        float d1 = depth[ranks_depth[p1]];
        float d2 = depth[ranks_depth[p2]];
        float d3 = depth[ranks_depth[p3]];
        float f0 = feat[(long)ranks_feat[p0] * C_CH + c];
        float f1 = feat[(long)ranks_feat[p1] * C_CH + c];
        float f2 = feat[(long)ranks_feat[p2] * C_CH + c];
        float f3 = feat[(long)ranks_feat[p3] * C_CH + c];
        acc += d0 * f0;
        acc += d1 * f1;
        acc += d2 * f2;
        acc += d3 * f3;
    }
    for (int i = len4; i < len; ++i) {
        int pp = p + i;
        acc += depth[ranks_depth[pp]] * feat[(long)ranks_feat[pp] * C_CH + c];
    }

    int bev = ranks_bev[start];
    out[(long)c * n_bev + bev] = acc;
}

extern "C" void kernel_launch(void* const* d_in, const int* in_sizes, int n_in,
                              void* d_out, int out_size, void* d_ws, size_t ws_size,
                              hipStream_t stream) {
    const float* depth = (const float*)d_in[0];
    const float* feat  = (const float*)d_in[1];
    const int* ranks_depth = (const int*)d_in[2];
    const int* ranks_feat  = (const int*)d_in[3];
    const int* ranks_bev   = (const int*)d_in[4];
    // d_in[5] = bev_feat_shape (5 ints, device) — shapes known statically.
    const int* interval_starts  = (const int*)d_in[6];
    const int* interval_lengths = (const int*)d_in[7];

    int n_intervals = in_sizes[6];
    int n_bev = out_size / C_CH;          // 16384
    float* out = (float*)d_out;

    // Zero the output: uncovered BEV cells must be 0 (harness poisons 0xAA).
    hipMemsetAsync(d_out, 0, (size_t)out_size * sizeof(float), stream);

    int total = n_intervals * C_CH;
    int block = 256;
    int grid = (total + block - 1) / block;
    bev_pool_interval_kernel<<<grid, block, 0, stream>>>(
        depth, feat, ranks_depth, ranks_feat, ranks_bev,
        interval_starts, interval_lengths, n_intervals, n_bev, out);
}

// Round 2
// 135.964 us; speedup vs baseline: 1.0874x; 1.0874x over previous
//
#include <hip/hip_runtime.h>
#include <hip/hip_bf16.h>

// BEV pool v2: segment-sum of depth[rd[p]] * feat_row[rf[p]] into BEV grid.
// One thread per (interval, channel-quad). C=80 -> 20 threads/interval,
// each accumulating a float4 of channels. Feat gathers are 16B/lane.

#define C_CH 80
#define CPT  20   // threads per interval = C_CH/4

__global__ void bev_pool_f4_kernel(
    const float*  __restrict__ depth,      // flat [B*N_CAM*D*HF*WF]
    const float4* __restrict__ feat4,      // flat rows [n_rows][20] of float4
    const int*    __restrict__ ranks_depth,
    const int*    __restrict__ ranks_feat,
    const int*    __restrict__ ranks_bev,
    const int*    __restrict__ interval_starts,
    const int*    __restrict__ interval_lengths,
    int n_intervals,
    int n_bev,                             // 16384
    float* __restrict__ out)               // [80][n_bev]
{
    int idx = blockIdx.x * blockDim.x + threadIdx.x;
    int total = n_intervals * CPT;
    if (idx >= total) return;

    int interval = idx / CPT;
    int c4       = idx - interval * CPT;   // 0..19

    int start = interval_starts[interval];
    int len   = interval_lengths[interval];

    float4 acc = make_float4(0.f, 0.f, 0.f, 0.f);

    int len4 = len & ~3;
    int i = 0;
    for (; i < len4; i += 4) {
        int p0 = start + i, p1 = p0 + 1, p2 = p0 + 2, p3 = p0 + 3;
        // Issue all index loads first (broadcast within interval's lanes).
        int rd0 = ranks_depth[p0], rd1 = ranks_depth[p1];
        int rd2 = ranks_depth[p2], rd3 = ranks_depth[p3];
        int rf0 = ranks_feat[p0],  rf1 = ranks_feat[p1];
        int rf2 = ranks_feat[p2],  rf3 = ranks_feat[p3];
        // Then all data loads (independent, 12 outstanding).
        float d0 = depth[rd0], d1 = depth[rd1], d2 = depth[rd2], d3 = depth[rd3];
        float4 f0 = feat4[(long)rf0 * CPT + c4];
        float4 f1 = feat4[(long)rf1 * CPT + c4];
        float4 f2 = feat4[(long)rf2 * CPT + c4];
        float4 f3 = feat4[(long)rf3 * CPT + c4];
        acc.x += d0 * f0.x; acc.y += d0 * f0.y; acc.z += d0 * f0.z; acc.w += d0 * f0.w;
        acc.x += d1 * f1.x; acc.y += d1 * f1.y; acc.z += d1 * f1.z; acc.w += d1 * f1.w;
        acc.x += d2 * f2.x; acc.y += d2 * f2.y; acc.z += d2 * f2.z; acc.w += d2 * f2.w;
        acc.x += d3 * f3.x; acc.y += d3 * f3.y; acc.z += d3 * f3.z; acc.w += d3 * f3.w;
    }
    for (; i < len; ++i) {
        int pp = start + i;
        float d = depth[ranks_depth[pp]];
        float4 f = feat4[(long)ranks_feat[pp] * CPT + c4];
        acc.x += d * f.x; acc.y += d * f.y; acc.z += d * f.z; acc.w += d * f.w;
    }

    int bev = ranks_bev[start];
    long o = (long)(c4 * 4) * n_bev + bev;
    out[o]             = acc.x;
    out[o + n_bev]     = acc.y;
    out[o + 2 * n_bev] = acc.z;
    out[o + 3 * n_bev] = acc.w;
}

extern "C" void kernel_launch(void* const* d_in, const int* in_sizes, int n_in,
                              void* d_out, int out_size, void* d_ws, size_t ws_size,
                              hipStream_t stream) {
    const float* depth = (const float*)d_in[0];
    const float4* feat4 = (const float4*)d_in[1];
    const int* ranks_depth = (const int*)d_in[2];
    const int* ranks_feat  = (const int*)d_in[3];
    const int* ranks_bev   = (const int*)d_in[4];
    // d_in[5] = bev_feat_shape (5 ints) — shapes known statically.
    const int* interval_starts  = (const int*)d_in[6];
    const int* interval_lengths = (const int*)d_in[7];

    int n_intervals = in_sizes[6];
    int n_bev = out_size / C_CH;          // 16384
    float* out = (float*)d_out;

    // Zero the output: uncovered BEV cells must be 0 (harness poisons 0xAA).
    hipMemsetAsync(d_out, 0, (size_t)out_size * sizeof(float), stream);

    int total = n_intervals * CPT;
    int block = 256;
    int grid = (total + block - 1) / block;
    bev_pool_f4_kernel<<<grid, block, 0, stream>>>(
        depth, feat4, ranks_depth, ranks_feat, ranks_bev,
        interval_starts, interval_lengths, n_intervals, n_bev, out);
}